// Round 2
// baseline (73.151 us; speedup 1.0000x reference)
//
#include <hip/hip_runtime.h>

// TT-core contraction: C[a,c,i,k,b,d] = sum_j A[a,i,j,b] * B[c,j,k,d]
// A: [RA0, M, N, RA1=64], B: [RB0, N, P, RB1=16]
// C flat index: ((((a*RB0 + c)*M + i)*P + k)*64 + b)*16 + d
//
// Single persistent kernel, grid-stride over a linear float4 index spanning
// the entire (contiguous) 5-core output. ~30 coalesced float4 stores per
// thread keep many writes in flight per wave (fill-kernel pattern, 7 TB/s).
// Inputs (~1.8 MB) are L1/L2 resident; per wave per j-step the A-read is one
// 64B line (16 consecutive dwords) and the B-read is one 64B line (4 distinct
// float4 broadcast to 16 lanes each). Write-BW-bound.

// float4-unit bases of each core's output region:
//  core0 [1,8,1,1024]    :       0 .. 2048
//  core1 [1024,8,2,1024] :    2048 .. 4196352
//  core2 [1024,8,5,1024] : 4196352 .. 14682112
//  core3 [1024,4,1,1024] :14682112 .. 15730688
//  core4 [1024,2,1,1]    :15730688 .. 15731200   (512 float4 = 2048 floats)
#define C1B 2048
#define C2B 4196352
#define C3B 14682112
#define C4B 15730688
#define TOTV 15731200

#define NBLOCKS 2048
#define NTHREADS 256
#define GSTRIDE (NBLOCKS * NTHREADS)  // 524288 = 2^19

// Generic core value for cores 0-3 (RA1=64, RB1=16 for all of them).
// INNER_V = 64 * (16/4) = 256 for every core -> pow2 shifts.
template<int M, int N, int P, int RB0>
__device__ __forceinline__ float4 tt_val(const float* __restrict__ A,
                                         const float* __restrict__ B,
                                         int vL) {
    const int iv    = vL & 255;
    const int outer = vL >> 8;
    const int d4 = iv & 3;
    const int b  = iv >> 2;
    const int k  = outer % P;        // P=5 -> magic mul; else pow2/1
    const int t  = outer / P;
    const int i  = t % M;            // M pow2
    const int t2 = t / M;
    const int c  = t2 % RB0;         // RB0 pow2
    const int a  = t2 / RB0;

    const float* Ap = A + ((a * M + i) * N) * 64 + b;       // + j*64
    const float* Bp = B + ((c * N) * P + k) * 16 + d4 * 4;  // + j*P*16

    float4 acc = make_float4(0.f, 0.f, 0.f, 0.f);
#pragma unroll
    for (int j = 0; j < N; ++j) {
        const float  aj = Ap[j * 64];
        const float4 bv = *reinterpret_cast<const float4*>(Bp + j * P * 16);
        acc.x = fmaf(aj, bv.x, acc.x);
        acc.y = fmaf(aj, bv.y, acc.y);
        acc.z = fmaf(aj, bv.z, acc.z);
        acc.w = fmaf(aj, bv.w, acc.w);
    }
    return acc;
}

// core4: x4 [64,2,8,1] * w4 [16,8,1,1] -> out [1024,2,1,1] flat o=(a*16+c)*2+i
// One float4 covers o = 4w..4w+3: a = w>>3 (no carry possible), c0 = (2w)&15,
// rows i=0,1 and cols c0, c0+1.
__device__ __forceinline__ float4 core4_val(const float* __restrict__ x4,
                                            const float* __restrict__ w4,
                                            int w) {
    const int a  = w >> 3;
    const int c0 = (2 * w) & 15;
    const float* xr0 = x4 + (a * 2 + 0) * 8;
    const float* xr1 = x4 + (a * 2 + 1) * 8;
    const float* wc0 = w4 + c0 * 8;
    const float* wc1 = w4 + (c0 + 1) * 8;
    float4 acc = make_float4(0.f, 0.f, 0.f, 0.f);
#pragma unroll
    for (int j = 0; j < 8; ++j) {
        acc.x = fmaf(xr0[j], wc0[j], acc.x);
        acc.y = fmaf(xr1[j], wc0[j], acc.y);
        acc.z = fmaf(xr0[j], wc1[j], acc.z);
        acc.w = fmaf(xr1[j], wc1[j], acc.w);
    }
    return acc;
}

__global__ __launch_bounds__(NTHREADS) void fused_tt_kernel(
    const float* __restrict__ x0, const float* __restrict__ x1,
    const float* __restrict__ x2, const float* __restrict__ x3,
    const float* __restrict__ x4,
    const float* __restrict__ w0, const float* __restrict__ w1,
    const float* __restrict__ w2, const float* __restrict__ w3,
    const float* __restrict__ w4,
    float* __restrict__ out)
{
    float4* __restrict__ out4 = reinterpret_cast<float4*>(out);
    const int gtid = blockIdx.x * NTHREADS + threadIdx.x;

    for (int v = gtid; v < TOTV; v += GSTRIDE) {
        float4 r;
        if (v >= C2B) {                 // most common side first
            if (v < C3B)       r = tt_val<8, 8, 5, 16>(x2, w2, v - C2B);
            else if (v < C4B)  r = tt_val<4, 4, 1, 16>(x3, w3, v - C3B);
            else               r = core4_val(x4, w4, v - C4B);
        } else {
            if (v >= C1B)      r = tt_val<8, 4, 2, 16>(x1, w1, v - C1B);
            else               r = tt_val<8, 3, 1, 1>(x0, w0, v);
        }
        out4[v] = r;
    }
}

extern "C" void kernel_launch(void* const* d_in, const int* in_sizes, int n_in,
                              void* d_out, int out_size, void* d_ws, size_t ws_size,
                              hipStream_t stream) {
    const float* x0 = (const float*)d_in[0];
    const float* x1 = (const float*)d_in[1];
    const float* x2 = (const float*)d_in[2];
    const float* x3 = (const float*)d_in[3];
    const float* x4 = (const float*)d_in[4];
    const float* w0 = (const float*)d_in[5];
    const float* w1 = (const float*)d_in[6];
    const float* w2 = (const float*)d_in[7];
    const float* w3 = (const float*)d_in[8];
    const float* w4 = (const float*)d_in[9];
    float* out = (float*)d_out;

    fused_tt_kernel<<<NBLOCKS, NTHREADS, 0, stream>>>(
        x0, x1, x2, x3, x4, w0, w1, w2, w3, w4, out);
}

// Round 4
// 71.602 us; speedup vs baseline: 1.0216x; 1.0216x over previous
//
#include <hip/hip_runtime.h>

// TT-core contraction: C[a,c,i,k,b,d] = sum_j A[a,i,j,b] * B[c,j,k,d]
// A: [RA0, M, N, RA1=64], B: [RB0, N, P, RB1=16]
// C flat index: ((((a*RB0 + c)*M + i)*P + k)*64 + b)*16 + d
//
// Round 4 = round 3 with the compile fix: use a native clang ext_vector f32x4
// (HIP float4 is a struct, rejected by __builtin_nontemporal_store).
// Theory: plain stores trigger write-allocate fetches (RFO) -- round 1/2 dur
// matched (252MB read + 252MB write)/7TB/s exactly. nt stores stream full
// lines to HBM without allocation -> halves HBM traffic.

typedef float f32x4 __attribute__((ext_vector_type(4)));

// float4-unit bases of each core's output region:
//  core0 [1,8,1,1024]    :       0 .. 2048
//  core1 [1024,8,2,1024] :    2048 .. 4196352
//  core2 [1024,8,5,1024] : 4196352 .. 14682112
//  core3 [1024,4,1,1024] :14682112 .. 15730688
//  core4 [1024,2,1,1]    :15730688 .. 15731200   (512 float4 = 2048 floats)
#define C1B 2048
#define C2B 4196352
#define C3B 14682112
#define C4B 15730688
#define TOTV 15731200

#define NBLOCKS 2048
#define NTHREADS 256
#define GSTRIDE (NBLOCKS * NTHREADS)  // 524288 = 2^19

// Generic core value for cores 0-3 (RA1=64, RB1=16 for all of them).
// INNER_V = 64 * (16/4) = 256 for every core -> pow2 shifts.
template<int M, int N, int P, int RB0>
__device__ __forceinline__ f32x4 tt_val(const float* __restrict__ A,
                                        const float* __restrict__ B,
                                        int vL) {
    const int iv    = vL & 255;
    const int outer = vL >> 8;
    const int d4 = iv & 3;
    const int b  = iv >> 2;
    const int k  = outer % P;        // P=5 -> magic mul; else pow2/1
    const int t  = outer / P;
    const int i  = t % M;            // M pow2
    const int t2 = t / M;
    const int c  = t2 % RB0;         // RB0 pow2
    const int a  = t2 / RB0;

    const float* Ap = A + ((a * M + i) * N) * 64 + b;       // + j*64
    const float* Bp = B + ((c * N) * P + k) * 16 + d4 * 4;  // + j*P*16

    f32x4 acc = (f32x4)(0.f);
#pragma unroll
    for (int j = 0; j < N; ++j) {
        const float aj = Ap[j * 64];
        const f32x4 bv = *reinterpret_cast<const f32x4*>(Bp + j * P * 16);
        acc.x = fmaf(aj, bv.x, acc.x);
        acc.y = fmaf(aj, bv.y, acc.y);
        acc.z = fmaf(aj, bv.z, acc.z);
        acc.w = fmaf(aj, bv.w, acc.w);
    }
    return acc;
}

// core4: x4 [64,2,8,1] * w4 [16,8,1,1] -> out [1024,2,1,1] flat o=(a*16+c)*2+i
// One float4 covers o = 4w..4w+3: a = w>>3, c0 = (2w)&15, rows i=0,1,
// cols c0, c0+1.
__device__ __forceinline__ f32x4 core4_val(const float* __restrict__ x4,
                                           const float* __restrict__ w4,
                                           int w) {
    const int a  = w >> 3;
    const int c0 = (2 * w) & 15;
    const float* xr0 = x4 + (a * 2 + 0) * 8;
    const float* xr1 = x4 + (a * 2 + 1) * 8;
    const float* wc0 = w4 + c0 * 8;
    const float* wc1 = w4 + (c0 + 1) * 8;
    f32x4 acc = (f32x4)(0.f);
#pragma unroll
    for (int j = 0; j < 8; ++j) {
        acc.x = fmaf(xr0[j], wc0[j], acc.x);
        acc.y = fmaf(xr1[j], wc0[j], acc.y);
        acc.z = fmaf(xr0[j], wc1[j], acc.z);
        acc.w = fmaf(xr1[j], wc1[j], acc.w);
    }
    return acc;
}

__global__ __launch_bounds__(NTHREADS) void fused_tt_kernel(
    const float* __restrict__ x0, const float* __restrict__ x1,
    const float* __restrict__ x2, const float* __restrict__ x3,
    const float* __restrict__ x4,
    const float* __restrict__ w0, const float* __restrict__ w1,
    const float* __restrict__ w2, const float* __restrict__ w3,
    const float* __restrict__ w4,
    float* __restrict__ out)
{
    f32x4* __restrict__ out4 = reinterpret_cast<f32x4*>(out);
    const int gtid = blockIdx.x * NTHREADS + threadIdx.x;

    for (int v = gtid; v < TOTV; v += GSTRIDE) {
        f32x4 r;
        if (v >= C2B) {                 // most common side first
            if (v < C3B)       r = tt_val<8, 8, 5, 16>(x2, w2, v - C2B);
            else if (v < C4B)  r = tt_val<4, 4, 1, 16>(x3, w3, v - C3B);
            else               r = core4_val(x4, w4, v - C4B);
        } else {
            if (v >= C1B)      r = tt_val<8, 4, 2, 16>(x1, w1, v - C1B);
            else               r = tt_val<8, 3, 1, 1>(x0, w0, v);
        }
        __builtin_nontemporal_store(r, out4 + v);
    }
}

extern "C" void kernel_launch(void* const* d_in, const int* in_sizes, int n_in,
                              void* d_out, int out_size, void* d_ws, size_t ws_size,
                              hipStream_t stream) {
    const float* x0 = (const float*)d_in[0];
    const float* x1 = (const float*)d_in[1];
    const float* x2 = (const float*)d_in[2];
    const float* x3 = (const float*)d_in[3];
    const float* x4 = (const float*)d_in[4];
    const float* w0 = (const float*)d_in[5];
    const float* w1 = (const float*)d_in[6];
    const float* w2 = (const float*)d_in[7];
    const float* w3 = (const float*)d_in[8];
    const float* w4 = (const float*)d_in[9];
    float* out = (float*)d_out;

    fused_tt_kernel<<<NBLOCKS, NTHREADS, 0, stream>>>(
        x0, x1, x2, x3, x4, w0, w1, w2, w3, w4, out);
}

// Round 5
// 53.396 us; speedup vs baseline: 1.3700x; 1.3410x over previous
//
#include <hip/hip_runtime.h>

// TT-core contraction: C[a,c,i,k,b,d] = sum_j A[a,i,j,b] * B[c,j,k,d]
// A: [RA0, M, N, RA1=64], B: [RB0, N, P, RB1=16]
// C flat f32x4 index: ((((a*RB0+c)*M+i)*P + k))*256 + b*4 + d4   (tid = b*4+d4)
//
// Round 5: locality restructure. Each block owns NT consecutive t=(a,c,i)
// slabs (NT*P outers = NT*P*4KB of contiguous output). A values live in
// registers (NT*N scalars/thread), B slabs staged once into LDS. Input reads
// no longer touch L1/L2 during the store stream -> fabric traffic ~= writes
// only (theory: prior 72us == (252MB read-churn + 252MB write)/7TB/s).

typedef float f32x4 __attribute__((ext_vector_type(4)));

// f32x4 bases of each core's output region:
#define O0 0
#define O1 2048
#define O2 4196352
#define O3 14682112
#define O4 15730688

// block ranges: core2 first (dominant)
#define B2 2048            // 40960 outers / (NT=4 * P=5)
#define B1 1024            // 16384 / (8*2)
#define B3 512             // 4096 / (8*1)
// core0: 1 block (8 outers), core4: 1 block
#define NBLK (B2 + B1 + B3 + 2)   // 3586

template<int M, int N, int P, int RB0, int NTT>
__device__ __forceinline__ void core_block(
    const float* __restrict__ A, const float* __restrict__ Bg,
    f32x4* __restrict__ out4, int bl, f32x4* __restrict__ Bl, int tid)
{
    constexpr int SLAB = N * P * 4;        // f32x4 per B c-slab
    const int t0 = bl * NTT;
    const int b  = tid >> 2;
    const int d4 = tid & 3;

    // --- A into registers (global, one-time; 64B-granule coalesced) ---
    float areg[NTT][N];
#pragma unroll
    for (int t = 0; t < NTT; ++t) {
        const int tt = t0 + t;
        const int i  = tt & (M - 1);
        const int a  = tt / (M * RB0);
        const float* Ap = A + ((a * M + i) * N) * 64 + b;
#pragma unroll
        for (int j = 0; j < N; ++j) areg[t][j] = Ap[j * 64];
    }

    // --- B slabs into LDS (per-t duplication keeps indexing trivial) ---
    const f32x4* Bg4 = reinterpret_cast<const f32x4*>(Bg);
#pragma unroll
    for (int t = 0; t < NTT; ++t) {
        const int tt = t0 + t;
        const int c  = (tt / M) & (RB0 - 1);
        for (int r = tid; r < SLAB; r += 256)
            Bl[t * SLAB + r] = Bg4[c * SLAB + r];
    }
    __syncthreads();

    // --- compute + streaming stores ---
#pragma unroll
    for (int t = 0; t < NTT; ++t) {
#pragma unroll
        for (int k = 0; k < P; ++k) {
            f32x4 acc = (f32x4)(0.f);
#pragma unroll
            for (int j = 0; j < N; ++j)
                acc += areg[t][j] * Bl[t * SLAB + (j * P + k) * 4 + d4];
            __builtin_nontemporal_store(
                acc, out4 + (((t0 + t) * P + k) * 256 + tid));
        }
    }
}

// core4: x4 [64,2,8,1] * w4 [16,8,1,1] -> out [1024,2,1,1]; o=(a*16+c)*2+i
__device__ __forceinline__ f32x4 core4_val(const float* __restrict__ x4,
                                           const float* __restrict__ w4,
                                           int w) {
    const int a  = w >> 3;
    const int c0 = (2 * w) & 15;
    const float* xr0 = x4 + (a * 2 + 0) * 8;
    const float* xr1 = x4 + (a * 2 + 1) * 8;
    const float* wc0 = w4 + c0 * 8;
    const float* wc1 = w4 + (c0 + 1) * 8;
    f32x4 acc = (f32x4)(0.f);
#pragma unroll
    for (int j = 0; j < 8; ++j) {
        acc.x = fmaf(xr0[j], wc0[j], acc.x);
        acc.y = fmaf(xr1[j], wc0[j], acc.y);
        acc.z = fmaf(xr0[j], wc1[j], acc.z);
        acc.w = fmaf(xr1[j], wc1[j], acc.w);
    }
    return acc;
}

__global__ __launch_bounds__(256) void fused_tt_kernel(
    const float* __restrict__ x0, const float* __restrict__ x1,
    const float* __restrict__ x2, const float* __restrict__ x3,
    const float* __restrict__ x4,
    const float* __restrict__ w0, const float* __restrict__ w1,
    const float* __restrict__ w2, const float* __restrict__ w3,
    const float* __restrict__ w4,
    float* __restrict__ out)
{
    __shared__ f32x4 Bl[640];              // 10 KB max (core2: 4 slabs x 160)
    const int blk = blockIdx.x;
    const int tid = threadIdx.x;
    f32x4* o4 = reinterpret_cast<f32x4*>(out);

    if (blk < B2) {
        core_block<8, 8, 5, 16, 4>(x2, w2, o4 + O2, blk, Bl, tid);
    } else if (blk < B2 + B1) {
        core_block<8, 4, 2, 16, 8>(x1, w1, o4 + O1, blk - B2, Bl, tid);
    } else if (blk < B2 + B1 + B3) {
        core_block<4, 4, 1, 16, 8>(x3, w3, o4 + O3, blk - B2 - B1, Bl, tid);
    } else if (blk == B2 + B1 + B3) {
        core_block<8, 3, 1, 1, 8>(x0, w0, o4 + O0, 0, Bl, tid);
    } else {
        // core4: 512 f32x4, one block, 2 iters
#pragma unroll
        for (int it = 0; it < 2; ++it) {
            const int w = it * 256 + tid;
            __builtin_nontemporal_store(core4_val(x4, w4, w), o4 + O4 + w);
        }
    }
}

extern "C" void kernel_launch(void* const* d_in, const int* in_sizes, int n_in,
                              void* d_out, int out_size, void* d_ws, size_t ws_size,
                              hipStream_t stream) {
    const float* x0 = (const float*)d_in[0];
    const float* x1 = (const float*)d_in[1];
    const float* x2 = (const float*)d_in[2];
    const float* x3 = (const float*)d_in[3];
    const float* x4 = (const float*)d_in[4];
    const float* w0 = (const float*)d_in[5];
    const float* w1 = (const float*)d_in[6];
    const float* w2 = (const float*)d_in[7];
    const float* w3 = (const float*)d_in[8];
    const float* w4 = (const float*)d_in[9];
    float* out = (float*)d_out;

    fused_tt_kernel<<<NBLK, 256, 0, stream>>>(
        x0, x1, x2, x3, x4, w0, w1, w2, w3, w4, out);
}

// Round 6
// 52.539 us; speedup vs baseline: 1.3923x; 1.0163x over previous
//
#include <hip/hip_runtime.h>

// TT-core contraction: C[a,c,i,k,b,d] = sum_j A[a,i,j,b] * B[c,j,k,d]
// A: [RA0, M, N, RA1=64], B: [RB0, N, P, RB1=16]
// C flat f32x4 index: (((a*RB0+c)*M+i)*P + k)*256 + tid   (tid = b*4+d4)
//
// Round 6 delta vs round 5: B-values hoisted out of the t-loop. Within a
// block, t's grouped by shared c (NTC = min(NTT, M) consecutive t share
// (a,c)); per (group,k) the N B f32x4's are loaded from LDS into registers
// ONCE and reused across all NTC t's -> 4x fewer ds_read_b128 (core2:
// 160->40/thread), LDS pipe fully hidden under the nt store stream.
// Also stage only the distinct c-slabs (core2: 2.5KB vs 10KB).

typedef float f32x4 __attribute__((ext_vector_type(4)));

// f32x4 bases of each core's output region:
#define O0 0
#define O1 2048
#define O2 4196352
#define O3 14682112
#define O4 15730688

// block ranges: core2 first (dominant)
#define B2 2048            // 40960 outers / (NT=4 * P=5)
#define B1 1024            // 16384 / (8*2)
#define B3 512             // 4096 / (8*1)
#define NBLK (B2 + B1 + B3 + 2)   // + core0, core4

template<int M, int N, int P, int RB0, int NTT>
__device__ __forceinline__ void core_block(
    const float* __restrict__ A, const float* __restrict__ Bg,
    f32x4* __restrict__ out4, int bl, f32x4* __restrict__ Bl, int tid)
{
    constexpr int SLAB = N * P * 4;               // f32x4 per B c-slab
    constexpr int NTC  = (NTT < M) ? NTT : M;     // t's sharing one c
    constexpr int NG   = NTT / NTC;               // distinct c groups
    const int t0 = bl * NTT;
    const int b  = tid >> 2;
    const int d4 = tid & 3;

    // --- A into registers (one-time; 64B-granule, L1/L2-served) ---
    float areg[NTT][N];
#pragma unroll
    for (int t = 0; t < NTT; ++t) {
        const int tt = t0 + t;
        const int i  = tt & (M - 1);
        const int a  = tt / (M * RB0);
        const float* Ap = A + ((a * M + i) * N) * 64 + b;
#pragma unroll
        for (int j = 0; j < N; ++j) areg[t][j] = Ap[j * 64];
    }

    // --- distinct B c-slabs into LDS ---
    const f32x4* Bg4 = reinterpret_cast<const f32x4*>(Bg);
#pragma unroll
    for (int g = 0; g < NG; ++g) {
        const int c = ((t0 + g * NTC) / M) & (RB0 - 1);
        for (int r = tid; r < SLAB; r += 256)
            Bl[g * SLAB + r] = Bg4[c * SLAB + r];
    }
    __syncthreads();

    // --- compute + streaming stores; B hoisted per (group,k) ---
#pragma unroll
    for (int g = 0; g < NG; ++g) {
#pragma unroll
        for (int k = 0; k < P; ++k) {
            f32x4 Bk[N];
#pragma unroll
            for (int j = 0; j < N; ++j)
                Bk[j] = Bl[g * SLAB + (j * P + k) * 4 + d4];
#pragma unroll
            for (int tl = 0; tl < NTC; ++tl) {
                const int t = g * NTC + tl;
                f32x4 acc = (f32x4)(0.f);
#pragma unroll
                for (int j = 0; j < N; ++j)
                    acc += areg[t][j] * Bk[j];
                __builtin_nontemporal_store(
                    acc, out4 + (((t0 + t) * P + k) * 256 + tid));
            }
        }
    }
}

// core4: x4 [64,2,8,1] * w4 [16,8,1,1] -> out [1024,2,1,1]; o=(a*16+c)*2+i
__device__ __forceinline__ f32x4 core4_val(const float* __restrict__ x4,
                                           const float* __restrict__ w4,
                                           int w) {
    const int a  = w >> 3;
    const int c0 = (2 * w) & 15;
    const float* xr0 = x4 + (a * 2 + 0) * 8;
    const float* xr1 = x4 + (a * 2 + 1) * 8;
    const float* wc0 = w4 + c0 * 8;
    const float* wc1 = w4 + (c0 + 1) * 8;
    f32x4 acc = (f32x4)(0.f);
#pragma unroll
    for (int j = 0; j < 8; ++j) {
        acc.x = fmaf(xr0[j], wc0[j], acc.x);
        acc.y = fmaf(xr1[j], wc0[j], acc.y);
        acc.z = fmaf(xr0[j], wc1[j], acc.z);
        acc.w = fmaf(xr1[j], wc1[j], acc.w);
    }
    return acc;
}

__global__ __launch_bounds__(256) void fused_tt_kernel(
    const float* __restrict__ x0, const float* __restrict__ x1,
    const float* __restrict__ x2, const float* __restrict__ x3,
    const float* __restrict__ x4,
    const float* __restrict__ w0, const float* __restrict__ w1,
    const float* __restrict__ w2, const float* __restrict__ w3,
    const float* __restrict__ w4,
    float* __restrict__ out)
{
    __shared__ f32x4 Bl[320];              // core3: 2 slabs x 16 = tiny; core2: 160
    const int blk = blockIdx.x;
    const int tid = threadIdx.x;
    f32x4* o4 = reinterpret_cast<f32x4*>(out);

    if (blk < B2) {
        core_block<8, 8, 5, 16, 4>(x2, w2, o4 + O2, blk, Bl, tid);
    } else if (blk < B2 + B1) {
        core_block<8, 4, 2, 16, 8>(x1, w1, o4 + O1, blk - B2, Bl, tid);
    } else if (blk < B2 + B1 + B3) {
        core_block<4, 4, 1, 16, 8>(x3, w3, o4 + O3, blk - B2 - B1, Bl, tid);
    } else if (blk == B2 + B1 + B3) {
        core_block<8, 3, 1, 1, 8>(x0, w0, o4 + O0, 0, Bl, tid);
    } else {
        // core4: 512 f32x4, one block, 2 iters
#pragma unroll
        for (int it = 0; it < 2; ++it) {
            const int w = it * 256 + tid;
            __builtin_nontemporal_store(core4_val(x4, w4, w), o4 + O4 + w);
        }
    }
}

extern "C" void kernel_launch(void* const* d_in, const int* in_sizes, int n_in,
                              void* d_out, int out_size, void* d_ws, size_t ws_size,
                              hipStream_t stream) {
    const float* x0 = (const float*)d_in[0];
    const float* x1 = (const float*)d_in[1];
    const float* x2 = (const float*)d_in[2];
    const float* x3 = (const float*)d_in[3];
    const float* x4 = (const float*)d_in[4];
    const float* w0 = (const float*)d_in[5];
    const float* w1 = (const float*)d_in[6];
    const float* w2 = (const float*)d_in[7];
    const float* w3 = (const float*)d_in[8];
    const float* w4 = (const float*)d_in[9];
    float* out = (float*)d_out;

    fused_tt_kernel<<<NBLK, 256, 0, stream>>>(
        x0, x1, x2, x3, x4, w0, w1, w2, w3, w4, out);
}

// Round 7
// 43.636 us; speedup vs baseline: 1.6764x; 1.2040x over previous
//
#include <hip/hip_runtime.h>

// TT-core contraction: C[a,c,i,k,b,d] = sum_j A[a,i,j,b] * B[c,j,k,d]
// A: [RA0, M, N, RA1=64], B: [RB0, N, P, RB1=16]
// C flat f32x4 index: (((a*RB0+c)*M+i)*P + k)*256 + tid   (tid = b*4+d4)
//
// Round 7 delta vs round 6: PLAIN stores (drop nontemporal). Fill kernel
// proves full-line plain stores don't RFO (983MB written, 21MB fetched), and
// the 252MB output fits the 256MB memory-side L3 -> cached writeback path
// should stream at fabric speed (~7TB/s) and, in graph-replay steady state,
// hit already-dirty L3 lines. nt forced everything to HBM at ~4.8TB/s.

typedef float f32x4 __attribute__((ext_vector_type(4)));

// f32x4 bases of each core's output region:
#define O0 0
#define O1 2048
#define O2 4196352
#define O3 14682112
#define O4 15730688

// block ranges: core2 first (dominant)
#define B2 2048            // 40960 outers / (NT=4 * P=5)
#define B1 1024            // 16384 / (8*2)
#define B3 512             // 4096 / (8*1)
#define NBLK (B2 + B1 + B3 + 2)   // + core0, core4

template<int M, int N, int P, int RB0, int NTT>
__device__ __forceinline__ void core_block(
    const float* __restrict__ A, const float* __restrict__ Bg,
    f32x4* __restrict__ out4, int bl, f32x4* __restrict__ Bl, int tid)
{
    constexpr int SLAB = N * P * 4;               // f32x4 per B c-slab
    constexpr int NTC  = (NTT < M) ? NTT : M;     // t's sharing one c
    constexpr int NG   = NTT / NTC;               // distinct c groups
    const int t0 = bl * NTT;
    const int b  = tid >> 2;
    const int d4 = tid & 3;

    // --- A into registers (one-time; 64B-granule, L1/L2-served) ---
    float areg[NTT][N];
#pragma unroll
    for (int t = 0; t < NTT; ++t) {
        const int tt = t0 + t;
        const int i  = tt & (M - 1);
        const int a  = tt / (M * RB0);
        const float* Ap = A + ((a * M + i) * N) * 64 + b;
#pragma unroll
        for (int j = 0; j < N; ++j) areg[t][j] = Ap[j * 64];
    }

    // --- distinct B c-slabs into LDS ---
    const f32x4* Bg4 = reinterpret_cast<const f32x4*>(Bg);
#pragma unroll
    for (int g = 0; g < NG; ++g) {
        const int c = ((t0 + g * NTC) / M) & (RB0 - 1);
        for (int r = tid; r < SLAB; r += 256)
            Bl[g * SLAB + r] = Bg4[c * SLAB + r];
    }
    __syncthreads();

    // --- compute + streaming stores; B hoisted per (group,k) ---
#pragma unroll
    for (int g = 0; g < NG; ++g) {
#pragma unroll
        for (int k = 0; k < P; ++k) {
            f32x4 Bk[N];
#pragma unroll
            for (int j = 0; j < N; ++j)
                Bk[j] = Bl[g * SLAB + (j * P + k) * 4 + d4];
#pragma unroll
            for (int tl = 0; tl < NTC; ++tl) {
                const int t = g * NTC + tl;
                f32x4 acc = (f32x4)(0.f);
#pragma unroll
                for (int j = 0; j < N; ++j)
                    acc += areg[t][j] * Bk[j];
                out4[((t0 + t) * P + k) * 256 + tid] = acc;
            }
        }
    }
}

// core4: x4 [64,2,8,1] * w4 [16,8,1,1] -> out [1024,2,1,1]; o=(a*16+c)*2+i
__device__ __forceinline__ f32x4 core4_val(const float* __restrict__ x4,
                                           const float* __restrict__ w4,
                                           int w) {
    const int a  = w >> 3;
    const int c0 = (2 * w) & 15;
    const float* xr0 = x4 + (a * 2 + 0) * 8;
    const float* xr1 = x4 + (a * 2 + 1) * 8;
    const float* wc0 = w4 + c0 * 8;
    const float* wc1 = w4 + (c0 + 1) * 8;
    f32x4 acc = (f32x4)(0.f);
#pragma unroll
    for (int j = 0; j < 8; ++j) {
        acc.x = fmaf(xr0[j], wc0[j], acc.x);
        acc.y = fmaf(xr1[j], wc0[j], acc.y);
        acc.z = fmaf(xr0[j], wc1[j], acc.z);
        acc.w = fmaf(xr1[j], wc1[j], acc.w);
    }
    return acc;
}

__global__ __launch_bounds__(256) void fused_tt_kernel(
    const float* __restrict__ x0, const float* __restrict__ x1,
    const float* __restrict__ x2, const float* __restrict__ x3,
    const float* __restrict__ x4,
    const float* __restrict__ w0, const float* __restrict__ w1,
    const float* __restrict__ w2, const float* __restrict__ w3,
    const float* __restrict__ w4,
    float* __restrict__ out)
{
    __shared__ f32x4 Bl[320];              // core2: 1 slab x 160 f32x4 = 2.5KB
    const int blk = blockIdx.x;
    const int tid = threadIdx.x;
    f32x4* o4 = reinterpret_cast<f32x4*>(out);

    if (blk < B2) {
        core_block<8, 8, 5, 16, 4>(x2, w2, o4 + O2, blk, Bl, tid);
    } else if (blk < B2 + B1) {
        core_block<8, 4, 2, 16, 8>(x1, w1, o4 + O1, blk - B2, Bl, tid);
    } else if (blk < B2 + B1 + B3) {
        core_block<4, 4, 1, 16, 8>(x3, w3, o4 + O3, blk - B2 - B1, Bl, tid);
    } else if (blk == B2 + B1 + B3) {
        core_block<8, 3, 1, 1, 8>(x0, w0, o4 + O0, 0, Bl, tid);
    } else {
        // core4: 512 f32x4, one block, 2 iters
#pragma unroll
        for (int it = 0; it < 2; ++it) {
            const int w = it * 256 + tid;
            o4[O4 + w] = core4_val(x4, w4, w);
        }
    }
}

extern "C" void kernel_launch(void* const* d_in, const int* in_sizes, int n_in,
                              void* d_out, int out_size, void* d_ws, size_t ws_size,
                              hipStream_t stream) {
    const float* x0 = (const float*)d_in[0];
    const float* x1 = (const float*)d_in[1];
    const float* x2 = (const float*)d_in[2];
    const float* x3 = (const float*)d_in[3];
    const float* x4 = (const float*)d_in[4];
    const float* w0 = (const float*)d_in[5];
    const float* w1 = (const float*)d_in[6];
    const float* w2 = (const float*)d_in[7];
    const float* w3 = (const float*)d_in[8];
    const float* w4 = (const float*)d_in[9];
    float* out = (float*)d_out;

    fused_tt_kernel<<<NBLK, 256, 0, stream>>>(
        x0, x1, x2, x3, x4, w0, w1, w2, w3, w4, out);
}